// Round 2
// 108.770 us; speedup vs baseline: 1.0604x; 1.0604x over previous
//
#include <hip/hip_runtime.h>

typedef short v8s __attribute__((ext_vector_type(8)));
typedef float v4f __attribute__((ext_vector_type(4)));
typedef float v16f __attribute__((ext_vector_type(16)));

// RNE float -> bf16 (matches float_quantize(exp=8, man=7) for these inputs).
__device__ __forceinline__ unsigned short rne_bf16(float f) {
  unsigned u = __float_as_uint(f);
  return (unsigned short)((u + 0x7fffu + ((u >> 16) & 1u)) >> 16);
}
__device__ __forceinline__ float qbf(float f) {
  return __uint_as_float(((unsigned)rne_bf16(f)) << 16);
}

#define CS 72  // LDS col stride (shorts): 144 B; conflict-benign, b128-aligned

// ---------------------------------------------------------------------------
// wprep: 32 blocks. weights -> fragment-major Wt2:
//   Wt2[((pos*4 + kk)*4 + n>>5)*512 + lane*8 + (c&7)],
//   lane = (n&31) + 32*((c>>3)&1), kk = c>>4
// so conv's W loads are single fully-coalesced 1024-B v8s instructions.
// ---------------------------------------------------------------------------
__global__ __launch_bounds__(256) void wprep(const float* __restrict__ w,
                                             unsigned short* __restrict__ Wt2) {
  int t = blockIdx.x * 256 + threadIdx.x;  // 0..8191 = n*64 + c
  int n = t >> 6, c = t & 63;
  int kk = c >> 4;
  int lane = (n & 31) + 32 * ((c >> 3) & 1);
  const float* src = w + (size_t)t * 9;
#pragma unroll
  for (int pos = 0; pos < 9; ++pos) {
    int idx = (((pos * 4 + kk) * 4 + (n >> 5)) << 9) + lane * 8 + (c & 7);
    Wt2[idx] = rne_bf16(src[pos]);
  }
}

// ---------------------------------------------------------------------------
// conv (fused): grid (16 [14 live quads], 2 ch-halves, 32 b), 256 thr = 4 waves.
// quad dim padded to 16 so chh twins differ by 16 in dispatch id == same XCD L2
// (both halves read the same x rows; x is 25.7 MB -> L2/L3 resident).
// Staging reads x fp32 NCHW directly, quantizes RNE->bf16, transposes into
// xs[6 rows][58 cols][64 c] with zeroed pad borders (no Xp intermediate).
// Lane map c8=i&7 innermost: ds_write_b128 conflict-free (8 lanes = 128 B
// contiguous), global dwordx4 in 128-B segments per channel-octet.
// Compute/epilogue unchanged from the verified kernel.
// ---------------------------------------------------------------------------
__global__ __launch_bounds__(256, 3) void conv(const float* __restrict__ x,
                                               const unsigned short* __restrict__ Wt2,
                                               const float* __restrict__ bias,
                                               float* __restrict__ out) {
  const int quad = blockIdx.x;
  if (quad >= 14) return;  // grid padded 14->16 for XCD pairing of chh twins

  __shared__ __align__(16) char smem[6 * 58 * CS * 2 + 256];
  unsigned short* xs = (unsigned short*)smem;      // [6 rows][58 cols][64 c]
  float* fbuf = (float*)smem;                      // epilogue union: [32 ch][228]
  float* qb = (float*)(smem + 6 * 58 * CS * 2);    // 64 quantized biases

  const int chh = blockIdx.y, b = blockIdx.z;
  const int oh0 = quad * 4;
  const int ch_base = chh * 64;
  const int tid = threadIdx.x;
  const int wv = tid >> 6, lane = tid & 63;
  const int lj = lane & 31, lh = lane >> 5;
  const int lj1 = 28 + (lj < 27 ? lj : 27);  // sp-tile1 col offset (clamped)

  if (tid < 64) qb[tid] = qbf(bias[ch_base + tid]);

  // ---- fused staging: x fp32 -> RNE bf16 -> xs (transposed), borders zeroed
  // 672 quad-slots = 6 rows * 8 chan-octets * 14 w-quads; 4 w per thread-slot.
  const float* xb0 = x + (size_t)b * 64 * 3136;
#pragma unroll
  for (int it = 0; it < 3; ++it) {
    int i = it * 256 + tid;
    if (i < 672) {
      int c8 = i & 7, jj = i >> 3;        // c8 innermost: LDS-conflict-free
      int r = jj / 14, wq = jj - r * 14;  // r: 0..5, wq: 0..13
      int h_in = oh0 + r - 1;             // input row (pad rows -> zeros)
      unsigned short* dstp = &xs[(r * 58 + 1 + wq * 4) * CS + c8 * 8];
      if ((unsigned)h_in < 56u) {
        const float* xb = xb0 + (size_t)(c8 * 8) * 3136 + h_in * 56 + wq * 4;
        v4f f[8];
#pragma unroll
        for (int jc = 0; jc < 8; ++jc) f[jc] = *(const v4f*)&xb[(size_t)jc * 3136];
#pragma unroll
        for (int k = 0; k < 4; ++k) {
          v8s pk;
#pragma unroll
          for (int jc = 0; jc < 8; ++jc) pk[jc] = (short)rne_bf16(f[jc][k]);
          *(v8s*)&dstp[k * CS] = pk;
        }
      } else {
        v8s z;
#pragma unroll
        for (int e = 0; e < 8; ++e) z[e] = 0;
#pragma unroll
        for (int k = 0; k < 4; ++k) *(v8s*)&dstp[k * CS] = z;
      }
    }
  }
  // zero col borders (w = -1 and 56): 6 rows * 2 cols * 8 octets = 96 slots
  if (tid < 96) {
    int r = tid >> 4, q = tid & 15;
    int col = (q >> 3) ? 57 : 0;
    v8s z;
#pragma unroll
    for (int e = 0; e < 8; ++e) z[e] = 0;
    *(v8s*)&xs[(r * 58 + col) * CS + (q & 7) * 8] = z;
  }

  // ---- W fragment prefetch: one coalesced 1024-B v8s load per (kk, ct).
  // Issued after staging so L2 latency overlaps the barrier wait (and peak
  // VGPR doesn't stack on staging temps).
  const unsigned short* wt0 = Wt2 + lane * 8;
  v8s wA[8], wB[8];
#define PREFETCH(POS, WBUF)                                                  \
  {                                                                          \
    _Pragma("unroll") for (int kk = 0; kk < 4; ++kk) {                       \
      WBUF[kk]     = *(const v8s*)(wt0 + ((((POS)*4 + kk) * 4 + chh * 2) << 9));     \
      WBUF[4 + kk] = *(const v8s*)(wt0 + ((((POS)*4 + kk) * 4 + chh * 2 + 1) << 9)); \
    }                                                                        \
  }
  PREFETCH(0, wA);
  PREFETCH(1, wB);
  __syncthreads();

  v16f acc[2][2];  // [ct][sp tile]
#pragma unroll
  for (int a = 0; a < 2; ++a)
#pragma unroll
    for (int s = 0; s < 2; ++s)
#pragma unroll
      for (int e = 0; e < 16; ++e) acc[a][s][e] = 0.0f;

#define COMPUTE(POS, WBUF)                                                     \
  {                                                                            \
    const int kh = (POS) / 3, kw = (POS) % 3;                                  \
    const unsigned short* p0 = xs + ((wv + kh) * 58 + kw + lj) * CS + lh * 8;  \
    const unsigned short* p1 = xs + ((wv + kh) * 58 + kw + lj1) * CS + lh * 8; \
    _Pragma("unroll") for (int kk = 0; kk < 4; ++kk) {                         \
      v8s f0 = *(const v8s*)(p0 + kk * 16);                                    \
      v8s f1 = *(const v8s*)(p1 + kk * 16);                                    \
      acc[0][0] = __builtin_amdgcn_mfma_f32_32x32x16_bf16(WBUF[kk], f0, acc[0][0], 0, 0, 0); \
      acc[0][1] = __builtin_amdgcn_mfma_f32_32x32x16_bf16(WBUF[kk], f1, acc[0][1], 0, 0, 0); \
      acc[1][0] = __builtin_amdgcn_mfma_f32_32x32x16_bf16(WBUF[4 + kk], f0, acc[1][0], 0, 0, 0); \
      acc[1][1] = __builtin_amdgcn_mfma_f32_32x32x16_bf16(WBUF[4 + kk], f1, acc[1][1], 0, 0, 0); \
    }                                                                          \
  }

  COMPUTE(0, wA); PREFETCH(2, wA);
  COMPUTE(1, wB); PREFETCH(3, wB);
  COMPUTE(2, wA); PREFETCH(4, wA);
  COMPUTE(3, wB); PREFETCH(5, wB);
  COMPUTE(4, wA); PREFETCH(6, wA);
  COMPUTE(5, wB); PREFETCH(7, wB);
  COMPUTE(6, wA); PREFETCH(8, wA);
  COMPUTE(7, wB);
  COMPUTE(8, wA);

  // ---- epilogue: LDS transpose -> full-line vectorized stores ----
  __syncthreads();  // all xs reads done; fbuf may now alias xs
#pragma unroll
  for (int ct = 0; ct < 2; ++ct) {
    if (lj < 28) {
#pragma unroll
      for (int e = 0; e < 16; ++e) {
        int chl = (e & 3) + 8 * (e >> 2) + 4 * lh;  // 0..31 (C/D layout, verified)
        fbuf[chl * 228 + wv * 56 + lj] = acc[ct][0][e];
        fbuf[chl * 228 + wv * 56 + 28 + lj] = acc[ct][1][e];
      }
    }
    __syncthreads();
#pragma unroll
    for (int p = 0; p < 8; ++p) {
      int i = p * 256 + tid;
      int chl = i >> 6, j = i & 63;
      if (j < 56) {
        v4f v = *(const v4f*)&fbuf[chl * 228 + j * 4];
        float bb = qb[ct * 32 + chl];
        v[0] += bb; v[1] += bb; v[2] += bb; v[3] += bb;
        float* dst = out + (size_t)(b * 128 + ch_base + ct * 32 + chl) * 3136 + quad * 224 + j * 4;
        *(v4f*)dst = v;
      }
    }
    if (ct == 0) __syncthreads();  // readers done before phase-1 overwrites fbuf
  }
}

extern "C" void kernel_launch(void* const* d_in, const int* in_sizes, int n_in,
                              void* d_out, int out_size, void* d_ws, size_t ws_size,
                              hipStream_t stream) {
  const float* x = (const float*)d_in[0];     // [32,64,56,56]
  const float* w = (const float*)d_in[1];     // [128,64,3,3]
  const float* bias = (const float*)d_in[2];  // [128]
  float* out = (float*)d_out;                 // [32,128,56,56] fp32

  unsigned short* Wt2 = (unsigned short*)d_ws;  // 147 KB only (Xp eliminated)

  wprep<<<32, 256, 0, stream>>>(w, Wt2);
  conv<<<dim3(16, 2, 32), 256, 0, stream>>>(x, Wt2, bias, out);
}